// Round 5
// baseline (753.838 us; speedup 1.0000x reference)
//
#include <hip/hip_runtime.h>
#include <math.h>

#define NGENES 50000
#define NEDGES 5000
#define NNZ_C 1600000
#define NPATH 500
#define DIM 128
#define BB 64
#define MM 200
#define BMN (BB * MM)
#define NBMW 1568          // bitmap words (50176 bits >= 50000)
#define CSRCAP 640000      // marked CSR entries ~363K expected
#define NCH 32             // histogram chunks
#define RNG 12512          // gene range per histogram role (4*12512 = 50048)
#define GSTRIDE 50048      // partial row stride
#define NT 8               // gene tiles (one per XCD)
#define TILESZ 6250        // genes per tile (3.2 MB of gene_embed -> fits 4 MB XCD L2)
#define PC 16              // placement chunks

// ---------------- wave helpers ----------------
__device__ inline float wred_sum(float x) {
#pragma unroll
  for (int off = 32; off > 0; off >>= 1) x += __shfl_down(x, off, 64);
  return x;
}
__device__ inline float wred_max(float x) {
#pragma unroll
  for (int off = 32; off > 0; off >>= 1) x = fmaxf(x, __shfl_down(x, off, 64));
  return x;
}
__device__ inline int wave_incl_scan(int x) {
  int lane = threadIdx.x & 63;
#pragma unroll
  for (int off = 1; off < 64; off <<= 1) {
    int y = __shfl_up(x, off, 64);
    if (lane >= off) x += y;
  }
  return x;
}

// mark genes referenced by gene_ids in a bitmap
__global__ void k_mark(const int* __restrict__ gene_ids, unsigned* __restrict__ bitmap) {
  int i = blockIdx.x * blockDim.x + threadIdx.x;
  if (i >= BMN) return;
  int g = gene_ids[i];
  atomicOr(bitmap + (g >> 5), 1u << (g & 31));
}

// Unified atomic-free histogram. grid = (NCH chunks, 17 roles), 1024 threads.
// roles 0-3 : Dv fp32 LDS histogram over gene range [role*RNG, +RNG)
// roles 4-7 : marked-gene count histogram over same ranges
// roles 8-15: (tile,edge) bucket count for tile = role-8 (5000 bins)
// role  16  : De fp32 col histogram (5000 bins)
__global__ void k_hist_all(const int* __restrict__ rows, const int* __restrict__ cols,
                           const float* __restrict__ vals, const unsigned* __restrict__ bitmap,
                           float* __restrict__ pdv, int* __restrict__ pcnt,
                           int* __restrict__ pbc, float* __restrict__ pde) {
  __shared__ char smem_raw[RNG * 4 + NBMW * 4];  // 56,320 B
  int c = blockIdx.x;
  int role = blockIdx.y;
  int tid = threadIdx.x;
  int lo = c * (NNZ_C / NCH);
  int hi = lo + (NNZ_C / NCH);
  if (role < 4) {
    float* hs = (float*)smem_raw;
    int rlo = role * RNG;
    for (int j = tid; j < RNG; j += 1024) hs[j] = 0.f;
    __syncthreads();
    for (int i = lo + tid; i < hi; i += 1024) {
      int r = rows[i];
      unsigned d = (unsigned)(r - rlo);
      if (d < RNG) atomicAdd(&hs[d], vals[i]);
    }
    __syncthreads();
    float* dst = pdv + (size_t)c * GSTRIDE + rlo;
    for (int j = tid; j < RNG; j += 1024) dst[j] = hs[j];
  } else if (role < 8) {
    int* hs = (int*)smem_raw;
    unsigned* bm = (unsigned*)(smem_raw + RNG * 4);
    int rlo = (role - 4) * RNG;
    for (int j = tid; j < RNG; j += 1024) hs[j] = 0;
    for (int j = tid; j < NBMW; j += 1024) bm[j] = bitmap[j];
    __syncthreads();
    for (int i = lo + tid; i < hi; i += 1024) {
      int r = rows[i];
      unsigned d = (unsigned)(r - rlo);
      if (d < RNG && ((bm[r >> 5] >> (r & 31)) & 1)) atomicAdd(&hs[d], 1);
    }
    __syncthreads();
    int* dst = pcnt + (size_t)c * GSTRIDE + rlo;
    for (int j = tid; j < RNG; j += 1024) dst[j] = hs[j];
  } else if (role < 16) {
    int t = role - 8;
    int* hs = (int*)smem_raw;
    for (int j = tid; j < NEDGES; j += 1024) hs[j] = 0;
    __syncthreads();
    for (int i = lo + tid; i < hi; i += 1024) {
      int r = rows[i];
      if (r / TILESZ == t) atomicAdd(&hs[cols[i]], 1);
    }
    __syncthreads();
    int* dst = pbc + (size_t)(c * NT + t) * NEDGES;
    for (int j = tid; j < NEDGES; j += 1024) dst[j] = hs[j];
  } else {
    float* hs = (float*)smem_raw;
    for (int j = tid; j < NEDGES; j += 1024) hs[j] = 0.f;
    __syncthreads();
    for (int i = lo + tid; i < hi; i += 1024) {
      atomicAdd(&hs[cols[i]], vals[i]);
    }
    __syncthreads();
    float* dst = pde + (size_t)c * NEDGES;
    for (int j = tid; j < NEDGES; j += 1024) dst[j] = hs[j];
  }
}

// merged reduction: genes (Dv,row_cnt), buckets (bucket_cnt), De
__global__ void k_reduce(const float* __restrict__ pdv, const int* __restrict__ pcnt,
                         const int* __restrict__ pbc, const float* __restrict__ pde,
                         float* __restrict__ Dv, int* __restrict__ row_cnt,
                         int* __restrict__ bucket_cnt, float* __restrict__ De) {
  int idx = blockIdx.x * 256 + threadIdx.x;
  if (idx < NGENES) {
    float s = 0.f;
    int n = 0;
    for (int c = 0; c < NCH; ++c) {
      s += pdv[(size_t)c * GSTRIDE + idx];
      n += pcnt[(size_t)c * GSTRIDE + idx];
    }
    Dv[idx] = s;
    row_cnt[idx] = n;
  } else if (idx < NGENES + NT * NEDGES) {
    int b = idx - NGENES;
    int n = 0;
    for (int c = 0; c < NCH; ++c) n += pbc[(size_t)c * (NT * NEDGES) + b];
    bucket_cnt[b] = n;
    if (b < NEDGES) {
      float s = 0.f;
      for (int c = 0; c < NCH; ++c) s += pde[(size_t)c * NEDGES + b];
      De[b] = s;
    }
  }
}

// blocked exclusive scan, one block per array (blockIdx 0: buckets, 1: rows)
__device__ inline void scan_excl_dev(const int* __restrict__ in, int* __restrict__ out, int n) {
  __shared__ int wsum[16];
  int t = threadIdx.x, lane = t & 63, wid = t >> 6;
  int nper = (n + 1023) / 1024;
  int base_i = t * nper;
  int s = 0;
  for (int j = 0; j < nper; ++j) {
    int i = base_i + j;
    if (i < n) s += in[i];
  }
  int incl = wave_incl_scan(s);
  if (lane == 63) wsum[wid] = incl;
  __syncthreads();
  int woff = 0;
  for (int w = 0; w < wid; ++w) woff += wsum[w];
  int run = woff + incl - s;
  for (int j = 0; j < nper; ++j) {
    int i = base_i + j;
    if (i < n) {
      out[i] = run;
      run += in[i];
    }
  }
}
__global__ void k_scan2(const int* __restrict__ bucket_cnt, int* __restrict__ bucket_start,
                        const int* __restrict__ row_cnt, int* __restrict__ row_start) {
  if (blockIdx.x == 0)
    scan_excl_dev(bucket_cnt, bucket_start, NT * NEDGES);
  else
    scan_excl_dev(row_cnt, row_start, NGENES);
}

// CSC placement into (tile,edge) buckets. grid (PC chunks, NT tiles), 1024 thr.
__global__ void k_place_csc(const int* __restrict__ rows, const int* __restrict__ cols,
                            const float* __restrict__ vals, const float* __restrict__ Dv,
                            const int* __restrict__ bucket_start, int* __restrict__ bucket_cur,
                            int2* __restrict__ csc) {
  __shared__ int cnt_s[NEDGES];
  __shared__ int base_s[NEDGES];
  int c = blockIdx.x, t = blockIdx.y, tid = threadIdx.x;
  int lo = c * (NNZ_C / PC);
  int hi = lo + (NNZ_C / PC);
  for (int j = tid; j < NEDGES; j += 1024) cnt_s[j] = 0;
  __syncthreads();
  for (int i = lo + tid; i < hi; i += 1024) {
    if (rows[i] / TILESZ == t) atomicAdd(&cnt_s[cols[i]], 1);
  }
  __syncthreads();
  for (int e = tid; e < NEDGES; e += 1024) {
    int n = cnt_s[e];
    if (n) {
      int b = t * NEDGES + e;
      base_s[e] = bucket_start[b] + atomicAdd(bucket_cur + b, n);
      cnt_s[e] = 0;
    }
  }
  __syncthreads();
  for (int i = lo + tid; i < hi; i += 1024) {
    int r = rows[i];
    if (r / TILESZ == t) {
      int cc = cols[i];
      float v = vals[i];
      float w = v / sqrtf(Dv[r] + 1e-6f);
      int pos = base_s[cc] + atomicAdd(&cnt_s[cc], 1);
      csc[pos] = make_int2(r, __float_as_int(w));
    }
  }
}

// CSR placement (marked rows only)
__global__ void k_place_csr(const int* __restrict__ rows, const int* __restrict__ cols,
                            const float* __restrict__ vals,
                            const int* __restrict__ row_start, int* __restrict__ row_cur,
                            const unsigned* __restrict__ bitmap, int2* __restrict__ csr) {
  __shared__ unsigned bm_s[NBMW];
  int tid = threadIdx.x;
  for (int i = tid; i < NBMW; i += 512) bm_s[i] = bitmap[i];
  __syncthreads();
  const int chunk = (NNZ_C + gridDim.x - 1) / gridDim.x;
  int lo = blockIdx.x * chunk;
  int hi = min(lo + chunk, NNZ_C);
  for (int i = lo + tid; i < hi; i += 512) {
    int r = rows[i];
    if ((bm_s[r >> 5] >> (r & 31)) & 1) {
      int p2 = row_start[r] + atomicAdd(row_cur + r, 1);
      if (p2 < CSRCAP) csr[p2] = make_int2(cols[i], __float_as_int(vals[i]));
    }
  }
}

// tiled edge pass: block bid -> tile t = bid&7 (XCD-affine), 8 edge-groups of 32 lanes.
// part[(t*NEDGES+e)*DIM + :] = sum over bucket(t,e) of w * gene_embed[r,:]
__global__ void k_edge_t(const int* __restrict__ bucket_start, const int* __restrict__ bucket_cnt,
                         const int2* __restrict__ csc, const float* __restrict__ gene_embed,
                         float* __restrict__ part) {
  int bid = blockIdx.x;
  int t = bid & 7;
  int eb = (bid >> 3) << 3;
  int grp = threadIdx.x >> 5, l = threadIdx.x & 31;
  int e = eb + grp;
  int b = t * NEDGES + e;
  int s = bucket_start[b];
  int end = s + bucket_cnt[b];
  float4 a0 = make_float4(0.f, 0.f, 0.f, 0.f);
  float4 a1 = make_float4(0.f, 0.f, 0.f, 0.f);
  float4 a2 = make_float4(0.f, 0.f, 0.f, 0.f);
  float4 a3 = make_float4(0.f, 0.f, 0.f, 0.f);
  int i = s;
  for (; i + 3 < end; i += 4) {
    int2 e0 = csc[i];
    int2 e1 = csc[i + 1];
    int2 e2 = csc[i + 2];
    int2 e3 = csc[i + 3];
    float4 x0 = *((const float4*)(gene_embed + (size_t)e0.x * DIM) + l);
    float4 x1 = *((const float4*)(gene_embed + (size_t)e1.x * DIM) + l);
    float4 x2 = *((const float4*)(gene_embed + (size_t)e2.x * DIM) + l);
    float4 x3 = *((const float4*)(gene_embed + (size_t)e3.x * DIM) + l);
    float w0 = __int_as_float(e0.y), w1 = __int_as_float(e1.y);
    float w2 = __int_as_float(e2.y), w3 = __int_as_float(e3.y);
    a0.x += w0 * x0.x; a0.y += w0 * x0.y; a0.z += w0 * x0.z; a0.w += w0 * x0.w;
    a1.x += w1 * x1.x; a1.y += w1 * x1.y; a1.z += w1 * x1.z; a1.w += w1 * x1.w;
    a2.x += w2 * x2.x; a2.y += w2 * x2.y; a2.z += w2 * x2.z; a2.w += w2 * x2.w;
    a3.x += w3 * x3.x; a3.y += w3 * x3.y; a3.z += w3 * x3.z; a3.w += w3 * x3.w;
  }
  for (; i < end; ++i) {
    int2 en = csc[i];
    float w = __int_as_float(en.y);
    float4 x = *((const float4*)(gene_embed + (size_t)en.x * DIM) + l);
    a0.x += w * x.x; a0.y += w * x.y; a0.z += w * x.z; a0.w += w * x.w;
  }
  a0.x += a1.x + a2.x + a3.x;
  a0.y += a1.y + a2.y + a3.y;
  a0.z += a1.z + a2.z + a3.z;
  a0.w += a1.w + a2.w + a3.w;
  *((float4*)(part + (size_t)b * DIM) + l) = a0;
}

// reduce 8 tile partials -> HXde[e,:] = (sum_t part) / (De[e]+1e-6)
__global__ void k_edge_red(const float* __restrict__ part, const float* __restrict__ De,
                           float* __restrict__ HXde) {
  int e = blockIdx.x, d = threadIdx.x;
  float s = 0.f;
#pragma unroll
  for (int t = 0; t < NT; ++t) s += part[((size_t)t * NEDGES + e) * DIM + d];
  HXde[(size_t)e * DIM + d] = s / (De[e] + 1e-6f);
}

// pass C fused with gene_ids gather (partial CSR); 4 groups, 2-deep unroll
__global__ void k_gene(const int* __restrict__ gene_ids, const int* __restrict__ row_start,
                       const int* __restrict__ row_cnt, const int2* __restrict__ csr,
                       const float* __restrict__ HXde, const float* __restrict__ Dv,
                       float* __restrict__ Xg) {
  __shared__ float4 red[4][32];
  int bm = blockIdx.x;
  int gene = gene_ids[bm];
  int s = row_start[gene], n = row_cnt[gene];
  int end = s + n;
  int g = threadIdx.x >> 5, l = threadIdx.x & 31;
  float4 a0 = make_float4(0.f, 0.f, 0.f, 0.f);
  float4 a1 = make_float4(0.f, 0.f, 0.f, 0.f);
  int i = s + g;
  for (; i + 4 < end; i += 8) {
    int2 e0 = csr[i];
    int2 e1 = csr[i + 4];
    float4 x0 = *((const float4*)(HXde + (size_t)e0.x * DIM) + l);
    float4 x1 = *((const float4*)(HXde + (size_t)e1.x * DIM) + l);
    float v0 = __int_as_float(e0.y), v1 = __int_as_float(e1.y);
    a0.x += v0 * x0.x; a0.y += v0 * x0.y; a0.z += v0 * x0.z; a0.w += v0 * x0.w;
    a1.x += v1 * x1.x; a1.y += v1 * x1.y; a1.z += v1 * x1.z; a1.w += v1 * x1.w;
  }
  for (; i < end; i += 4) {
    int2 en = csr[i];
    float v = __int_as_float(en.y);
    float4 x = *((const float4*)(HXde + (size_t)en.x * DIM) + l);
    a0.x += v * x.x; a0.y += v * x.y; a0.z += v * x.z; a0.w += v * x.w;
  }
  a0.x += a1.x; a0.y += a1.y; a0.z += a1.z; a0.w += a1.w;
  red[g][l] = a0;
  __syncthreads();
  if (g == 0) {
    float4 a = red[0][l], b = red[1][l], c = red[2][l], d = red[3][l];
    float dvg = 1.f / sqrtf(Dv[gene] + 1e-6f);
    float4 o;
    o.x = (a.x + b.x + c.x + d.x) * dvg;
    o.y = (a.y + b.y + c.y + d.y) * dvg;
    o.z = (a.z + b.z + c.z + d.z) * dvg;
    o.w = (a.w + b.w + c.w + d.w) * dvg;
    *((float4*)(Xg + (size_t)bm * DIM) + l) = o;
  }
}

// rep[b,p,d] = (sum_m Xg[b,m,d]*mask[m,p]) / max(cnt[p],1)
#define PT 20
__global__ void k_pathway(const int* __restrict__ gene_ids,
                          const float* __restrict__ gene_pathway,
                          const float* __restrict__ Xg, float* __restrict__ rep) {
  int b = blockIdx.y;
  int p0 = blockIdx.x * PT;
  int d = threadIdx.x;
  float acc[PT], cnt[PT];
#pragma unroll
  for (int pp = 0; pp < PT; ++pp) { acc[pp] = 0.f; cnt[pp] = 0.f; }
  for (int m = 0; m < MM; ++m) {
    int g = gene_ids[b * MM + m];
    float x = Xg[(size_t)(b * MM + m) * DIM + d];
    const float* mrow = gene_pathway + (size_t)g * NPATH + p0;
#pragma unroll
    for (int pp = 0; pp < PT; ++pp) {
      float mv = mrow[pp];
      acc[pp] += mv * x;
      cnt[pp] += mv;
    }
  }
#pragma unroll
  for (int pp = 0; pp < PT; ++pp) {
    rep[((size_t)b * NPATH + p0 + pp) * DIM + d] = acc[pp] / fmaxf(cnt[pp], 1.f);
  }
}

// ctxW[b,j] = sum_k ctx[b,k] * W1[D+k, j]
__global__ void k_ctxw(const int* __restrict__ context_ids,
                       const float* __restrict__ treatment_embed,
                       const float* __restrict__ W1, float* __restrict__ ctxW) {
  __shared__ float ctx_s[DIM];
  int b = blockIdx.x, j = threadIdx.x;
  ctx_s[j] = treatment_embed[context_ids[b] * DIM + j];
  __syncthreads();
  float acc = 0.f;
  for (int k = 0; k < DIM; ++k) acc += ctx_s[k] * W1[(DIM + k) * DIM + j];
  ctxW[b * DIM + j] = acc;
}

// scores[b,p] = tanh(rep@W1_top + ctxW + b1) @ W2 + b2
#define PT2 10
__global__ void k_attn(const float* __restrict__ rep, const float* __restrict__ ctxW,
                       const float* __restrict__ W1, const float* __restrict__ b1,
                       const float* __restrict__ W2, const float* __restrict__ b2,
                       float* __restrict__ scores) {
  __shared__ float in_s[PT2][DIM];
  __shared__ float part[PT2][2];
  int b = blockIdx.y;
  int p0 = blockIdx.x * PT2;
  int j = threadIdx.x;
  int lane = j & 63, wid = j >> 6;
#pragma unroll
  for (int pp = 0; pp < PT2; ++pp)
    in_s[pp][j] = rep[((size_t)b * NPATH + p0 + pp) * DIM + j];
  __syncthreads();
  float base = b1[j] + ctxW[b * DIM + j];
  float acc[PT2];
#pragma unroll
  for (int pp = 0; pp < PT2; ++pp) acc[pp] = base;
  for (int k = 0; k < DIM; ++k) {
    float w1 = W1[k * DIM + j];
#pragma unroll
    for (int pp = 0; pp < PT2; ++pp) acc[pp] += in_s[pp][k] * w1;
  }
  float w2 = W2[j];
#pragma unroll
  for (int pp = 0; pp < PT2; ++pp) {
    float t = tanhf(acc[pp]) * w2;
    t = wred_sum(t);
    if (lane == 0) part[pp][wid] = t;
  }
  __syncthreads();
  if (j < PT2) scores[b * NPATH + p0 + j] = part[j][0] + part[j][1] + b2[0];
}

// softmax + z0 + z + risk, one block per b (128 threads)
__global__ void k_final(const float* __restrict__ scores, const float* __restrict__ rep,
                        const float* __restrict__ latent_W, const float* __restrict__ latent_b,
                        const float* __restrict__ risk_W, const float* __restrict__ risk_b,
                        float* __restrict__ out) {
  __shared__ float w_s[NPATH];
  __shared__ float z0_s[DIM];
  __shared__ float red_max[2], red_sum[2], red_risk[2];
  int b = blockIdx.x, t = threadIdx.x;
  int lane = t & 63, wid = t >> 6;
  float lmax = -3.4e38f;
  for (int p = t; p < NPATH; p += 128) {
    float s = scores[b * NPATH + p];
    w_s[p] = s;
    lmax = fmaxf(lmax, s);
  }
  lmax = wred_max(lmax);
  if (lane == 0) red_max[wid] = lmax;
  __syncthreads();
  float bmax = fmaxf(red_max[0], red_max[1]);
  float lsum = 0.f;
  for (int p = t; p < NPATH; p += 128) {
    float e = expf(w_s[p] - bmax);
    w_s[p] = e;
    lsum += e;
  }
  lsum = wred_sum(lsum);
  if (lane == 0) red_sum[wid] = lsum;
  __syncthreads();
  float inv = 1.f / (red_sum[0] + red_sum[1]);
  float z0 = 0.f;
  int d = t;
#pragma unroll 4
  for (int p = 0; p < NPATH; ++p) z0 += w_s[p] * rep[((size_t)b * NPATH + p) * DIM + d];
  z0 *= inv;
  z0_s[d] = z0;
  __syncthreads();
  float z = latent_b[t];
  for (int dd = 0; dd < DIM; ++dd) z += z0_s[dd] * latent_W[dd * DIM + t];
  out[BB + b * DIM + t] = z;
  float r = z * risk_W[t];
  r = wred_sum(r);
  if (lane == 0) red_risk[wid] = r;
  __syncthreads();
  if (t == 0) out[b] = red_risk[0] + red_risk[1] + risk_b[0];
}

extern "C" void kernel_launch(void* const* d_in, const int* in_sizes, int n_in,
                              void* d_out, int out_size, void* d_ws, size_t ws_size,
                              hipStream_t stream) {
  const int* gene_ids = (const int*)d_in[0];
  const int* context_ids = (const int*)d_in[1];
  const int* H_rows = (const int*)d_in[2];
  const int* H_cols = (const int*)d_in[3];
  const float* H_vals = (const float*)d_in[4];
  const float* gene_embed = (const float*)d_in[5];
  const float* treatment_embed = (const float*)d_in[6];
  const float* gene_pathway = (const float*)d_in[7];
  const float* W1 = (const float*)d_in[8];
  const float* b1 = (const float*)d_in[9];
  const float* W2 = (const float*)d_in[10];
  const float* b2 = (const float*)d_in[11];
  const float* latent_W = (const float*)d_in[12];
  const float* latent_b = (const float*)d_in[13];
  const float* risk_W = (const float*)d_in[14];
  const float* risk_b = (const float*)d_in[15];
  float* out = (float*)d_out;

  char* ws = (char*)d_ws;
  // --- meta ---
  float* Dv = (float*)(ws + 0);                    // 200000 B
  float* De = (float*)(ws + 200000);               // 20000 -> 220000
  int* row_cnt = (int*)(ws + 220000);              // 200000 -> 420000
  int* row_start = (int*)(ws + 420000);            // 200000 -> 620000
  int* bucket_cnt = (int*)(ws + 620000);           // 160000 -> 780000
  int* bucket_start = (int*)(ws + 780000);         // 160000 -> 940000
  float* scores = (float*)(ws + 940000);           // 128000 -> 1068000
  float* ctxW = (float*)(ws + 1068000);            // 32768 -> 1100768 (pad->1100800)
  // --- memset zone ---
  int* row_cur = (int*)(ws + 1100800);             // 200000 -> 1300800
  int* bucket_cur = (int*)(ws + 1300800);          // 160000 -> 1460800
  unsigned* bitmap = (unsigned*)(ws + 1460800);    // 6272 -> 1467072
  // --- sparse structures ---
  int2* csc = (int2*)(ws + 1467072);               // 12800000 -> 14267072
  int2* csr = (int2*)(ws + 14267072);              // 5120000 -> 19387072
  float* HXde = (float*)(ws + 19387072);           // 2560000 -> 21947072
  // hist partials ALIAS csc/csr/HXde-head (dead before those are written):
  float* pdv = (float*)(ws + 1467072);             // 32*50048*4 -> 7873216
  int* pcnt = (int*)(ws + 7873216);                // 32*50048*4 -> 14279360
  int* pbc = (int*)(ws + 14279360);                // 32*8*5000*4 -> 19399360
  float* pde = (float*)(ws + 19399360);            // 32*5000*4 -> 20039360 (< 21947072 OK)
  // --- B region (part aliases Xg+rep; part dead before k_gene writes Xg) ---
  float* Xg = (float*)(ws + 21947072);             // 6553600 -> 28500672
  float* rep = (float*)(ws + 28500672);            // 16384000 -> 44884672
  float* part = (float*)(ws + 21947072);           // 8*5000*128*4 = 20480000 -> 42427072 (alias)

  hipMemsetAsync(ws + 1100800, 0, 366272, stream);  // row_cur, bucket_cur, bitmap

  k_mark<<<(BMN + 255) / 256, 256, 0, stream>>>(gene_ids, bitmap);
  k_hist_all<<<dim3(NCH, 17), 1024, 0, stream>>>(H_rows, H_cols, H_vals, bitmap,
                                                 pdv, pcnt, pbc, pde);
  k_reduce<<<(NGENES + NT * NEDGES + 255) / 256, 256, 0, stream>>>(
      pdv, pcnt, pbc, pde, Dv, row_cnt, bucket_cnt, De);
  k_scan2<<<2, 1024, 0, stream>>>(bucket_cnt, bucket_start, row_cnt, row_start);
  k_place_csc<<<dim3(PC, NT), 1024, 0, stream>>>(H_rows, H_cols, H_vals, Dv,
                                                 bucket_start, bucket_cur, csc);
  k_place_csr<<<128, 512, 0, stream>>>(H_rows, H_cols, H_vals, row_start, row_cur,
                                       bitmap, csr);
  k_edge_t<<<NEDGES, 256, 0, stream>>>(bucket_start, bucket_cnt, csc, gene_embed, part);
  k_edge_red<<<NEDGES, DIM, 0, stream>>>(part, De, HXde);
  k_gene<<<BMN, 128, 0, stream>>>(gene_ids, row_start, row_cnt, csr, HXde, Dv, Xg);
  k_pathway<<<dim3(NPATH / PT, BB), DIM, 0, stream>>>(gene_ids, gene_pathway, Xg, rep);
  k_ctxw<<<BB, DIM, 0, stream>>>(context_ids, treatment_embed, W1, ctxW);
  k_attn<<<dim3(NPATH / PT2, BB), DIM, 0, stream>>>(rep, ctxW, W1, b1, W2, b2, scores);
  k_final<<<BB, DIM, 0, stream>>>(scores, rep, latent_W, latent_b, risk_W, risk_b, out);
}

// Round 6
// 654.876 us; speedup vs baseline: 1.1511x; 1.1511x over previous
//
#include <hip/hip_runtime.h>
#include <math.h>

#define NGENES 50000
#define NEDGES 5000
#define NNZ_C 1600000
#define NPATH 500
#define DIM 128
#define BB 64
#define MM 200
#define BMN (BB * MM)
#define NBMW 1568          // bitmap words (50176 bits >= 50000)
#define CSRCAP 400000      // marked CSR entries ~240K expected
#define NCH 32             // row-hist chunks
#define CCH 256            // col-hist / placement chunks
#define RNG 12512          // gene range per hist role (4*12512 = 50048)
#define GSTRIDE 50048      // row partial stride

// ---------------- wave helpers ----------------
__device__ inline float wred_sum(float x) {
#pragma unroll
  for (int off = 32; off > 0; off >>= 1) x += __shfl_down(x, off, 64);
  return x;
}
__device__ inline float wred_max(float x) {
#pragma unroll
  for (int off = 32; off > 0; off >>= 1) x = fmaxf(x, __shfl_down(x, off, 64));
  return x;
}
__device__ inline int wave_incl_scan(int x) {
  int lane = threadIdx.x & 63;
#pragma unroll
  for (int off = 1; off < 64; off <<= 1) {
    int y = __shfl_up(x, off, 64);
    if (lane >= off) x += y;
  }
  return x;
}

// mark genes referenced by gene_ids in a bitmap
__global__ void k_mark(const int* __restrict__ gene_ids, unsigned* __restrict__ bitmap) {
  int i = blockIdx.x * blockDim.x + threadIdx.x;
  if (i >= BMN) return;
  int g = gene_ids[i];
  atomicOr(bitmap + (g >> 5), 1u << (g & 31));
}

// row-side histograms, atomic-free. grid (NCH, 8), 1024 thr.
// roles 0-3: Dv fp32 LDS hist over range [role*RNG,+RNG); roles 4-7: marked count.
__global__ void k_hist_row(const int* __restrict__ rows, const float* __restrict__ vals,
                           const unsigned* __restrict__ bitmap,
                           float* __restrict__ pdv, int* __restrict__ pcnt) {
  __shared__ char smem_raw[RNG * 4 + NBMW * 4];  // 56,320 B
  int c = blockIdx.x, role = blockIdx.y, tid = threadIdx.x;
  int lo = c * (NNZ_C / NCH), hi = lo + (NNZ_C / NCH);
  if (role < 4) {
    float* hs = (float*)smem_raw;
    int rlo = role * RNG;
    for (int j = tid; j < RNG; j += 1024) hs[j] = 0.f;
    __syncthreads();
    for (int i = lo + tid; i < hi; i += 1024) {
      int r = rows[i];
      unsigned d = (unsigned)(r - rlo);
      if (d < RNG) atomicAdd(&hs[d], vals[i]);
    }
    __syncthreads();
    float* dst = pdv + (size_t)c * GSTRIDE + rlo;
    for (int j = tid; j < RNG; j += 1024) dst[j] = hs[j];
  } else {
    int* hs = (int*)smem_raw;
    unsigned* bm = (unsigned*)(smem_raw + RNG * 4);
    int rlo = (role - 4) * RNG;
    for (int j = tid; j < RNG; j += 1024) hs[j] = 0;
    for (int j = tid; j < NBMW; j += 1024) bm[j] = bitmap[j];
    __syncthreads();
    for (int i = lo + tid; i < hi; i += 1024) {
      int r = rows[i];
      unsigned d = (unsigned)(r - rlo);
      if (d < RNG && ((bm[r >> 5] >> (r & 31)) & 1)) atomicAdd(&hs[d], 1);
    }
    __syncthreads();
    int* dst = pcnt + (size_t)c * GSTRIDE + rlo;
    for (int j = tid; j < RNG; j += 1024) dst[j] = hs[j];
  }
}

// col-side histogram partials, atomic-free. grid CCH, 1024 thr.
__global__ void k_hist_col(const int* __restrict__ cols, const float* __restrict__ vals,
                           int* __restrict__ pccnt, float* __restrict__ pcsum) {
  __shared__ int hc[NEDGES];
  __shared__ float hsf[NEDGES];
  int c = blockIdx.x, tid = threadIdx.x;
  for (int j = tid; j < NEDGES; j += 1024) { hc[j] = 0; hsf[j] = 0.f; }
  __syncthreads();
  int lo = c * (NNZ_C / CCH), hi = lo + (NNZ_C / CCH);
  for (int i = lo + tid; i < hi; i += 1024) {
    int e = cols[i];
    atomicAdd(&hc[e], 1);
    atomicAdd(&hsf[e], vals[i]);
  }
  __syncthreads();
  for (int j = tid; j < NEDGES; j += 1024) {
    pccnt[(size_t)c * NEDGES + j] = hc[j];
    pcsum[(size_t)c * NEDGES + j] = hsf[j];
  }
}

// reduce partials -> dv_inv, row_cnt, col_cnt, de_inv, per-chunk col prefix ccpre
__global__ void k_reduce(const float* __restrict__ pdv, const int* __restrict__ pcnt,
                         const int* __restrict__ pccnt, const float* __restrict__ pcsum,
                         float* __restrict__ dv_inv, int* __restrict__ row_cnt,
                         int* __restrict__ col_cnt, float* __restrict__ de_inv,
                         int* __restrict__ ccpre) {
  int idx = blockIdx.x * 256 + threadIdx.x;
  if (idx < NGENES) {
    float s = 0.f;
    int n = 0;
    for (int c = 0; c < NCH; ++c) {
      s += pdv[(size_t)c * GSTRIDE + idx];
      n += pcnt[(size_t)c * GSTRIDE + idx];
    }
    dv_inv[idx] = 1.f / sqrtf(s + 1e-6f);
    row_cnt[idx] = n;
  } else if (idx < NGENES + NEDGES) {
    int e = idx - NGENES;
    int run = 0;
    float s = 0.f;
    for (int c = 0; c < CCH; ++c) {
      ccpre[(size_t)c * NEDGES + e] = run;
      run += pccnt[(size_t)c * NEDGES + e];
      s += pcsum[(size_t)c * NEDGES + e];
    }
    col_cnt[e] = run;
    de_inv[e] = 1.f / (s + 1e-6f);
  }
}

// blocked exclusive scans (block 0: cols, block 1: rows)
__device__ inline void scan_excl_dev(const int* __restrict__ in, int* __restrict__ out, int n) {
  __shared__ int wsum[16];
  int t = threadIdx.x, lane = t & 63, wid = t >> 6;
  int nper = (n + 1023) / 1024;
  int base_i = t * nper;
  int s = 0;
  for (int j = 0; j < nper; ++j) {
    int i = base_i + j;
    if (i < n) s += in[i];
  }
  int incl = wave_incl_scan(s);
  if (lane == 63) wsum[wid] = incl;
  __syncthreads();
  int woff = 0;
  for (int w = 0; w < wid; ++w) woff += wsum[w];
  int run = woff + incl - s;
  for (int j = 0; j < nper; ++j) {
    int i = base_i + j;
    if (i < n) {
      out[i] = run;
      run += in[i];
    }
  }
}
__global__ void k_scan2(const int* __restrict__ col_cnt, int* __restrict__ col_start,
                        const int* __restrict__ row_cnt, int* __restrict__ row_start) {
  if (blockIdx.x == 0)
    scan_excl_dev(col_cnt, col_start, NEDGES);
  else
    scan_excl_dev(row_cnt, row_start, NGENES);
}

// Escaled[g,:] = gene_embed[g,:] * dv_inv[g]  (float4 over 1.6M vec4)
__global__ void k_escale(const float* __restrict__ ge, const float* __restrict__ dv_inv,
                         float* __restrict__ Esc) {
  int idx = blockIdx.x * 256 + threadIdx.x;  // float4 index
  int g = idx >> 5;                          // 32 float4 per gene
  float d = dv_inv[g];
  float4 x = ((const float4*)ge)[idx];
  x.x *= d; x.y *= d; x.z *= d; x.w *= d;
  ((float4*)Esc)[idx] = x;
}

// deterministic placement: csc via LDS-rank + per-chunk prefix (NO global atomics);
// csr for marked rows via ~240K global atomics. grid CCH, 1024 thr.
__global__ void k_place(const int* __restrict__ rows, const int* __restrict__ cols,
                        const float* __restrict__ vals, const int* __restrict__ col_start,
                        const int* __restrict__ ccpre, const int* __restrict__ row_start,
                        int* __restrict__ row_cur, const unsigned* __restrict__ bitmap,
                        int2* __restrict__ csc, int2* __restrict__ csr) {
  __shared__ int cnt_s[NEDGES];
  __shared__ unsigned bm_s[NBMW];
  int c = blockIdx.x, tid = threadIdx.x;
  for (int j = tid; j < NEDGES; j += 1024) cnt_s[j] = 0;
  for (int j = tid; j < NBMW; j += 1024) bm_s[j] = bitmap[j];
  __syncthreads();
  const int* cp = ccpre + (size_t)c * NEDGES;
  int lo = c * (NNZ_C / CCH), hi = lo + (NNZ_C / CCH);
  for (int i = lo + tid; i < hi; i += 1024) {
    int r = rows[i], e = cols[i];
    float v = vals[i];
    int rank = atomicAdd(&cnt_s[e], 1);
    csc[col_start[e] + cp[e] + rank] = make_int2(r, __float_as_int(v));
    if ((bm_s[r >> 5] >> (r & 31)) & 1) {
      int p2 = row_start[r] + atomicAdd(row_cur + r, 1);
      if (p2 < CSRCAP) csr[p2] = make_int2(e, __float_as_int(v));
    }
  }
}

// pass B: HXde[e,:] = de_inv[e] * sum_i v_i * Esc[r_i,:]
// 256 thr = 8 half-wave groups; 4-deep unroll = 32 gathers in flight per block (proven R4 form).
__global__ void k_edge(const int* __restrict__ col_start, const int2* __restrict__ csc,
                       const float* __restrict__ Esc, const float* __restrict__ de_inv,
                       float* __restrict__ HXde) {
  __shared__ float4 red[8][32];
  int e = blockIdx.x;
  int s = col_start[e];
  int end = (e == NEDGES - 1) ? NNZ_C : col_start[e + 1];
  int g = threadIdx.x >> 5, l = threadIdx.x & 31;
  float4 a0 = make_float4(0.f, 0.f, 0.f, 0.f);
  float4 a1 = make_float4(0.f, 0.f, 0.f, 0.f);
  float4 a2 = make_float4(0.f, 0.f, 0.f, 0.f);
  float4 a3 = make_float4(0.f, 0.f, 0.f, 0.f);
  int i = s + g;
  for (; i + 24 < end; i += 32) {
    int2 e0 = csc[i];
    int2 e1 = csc[i + 8];
    int2 e2 = csc[i + 16];
    int2 e3 = csc[i + 24];
    float4 x0 = *((const float4*)(Esc + (size_t)e0.x * DIM) + l);
    float4 x1 = *((const float4*)(Esc + (size_t)e1.x * DIM) + l);
    float4 x2 = *((const float4*)(Esc + (size_t)e2.x * DIM) + l);
    float4 x3 = *((const float4*)(Esc + (size_t)e3.x * DIM) + l);
    float w0 = __int_as_float(e0.y), w1 = __int_as_float(e1.y);
    float w2 = __int_as_float(e2.y), w3 = __int_as_float(e3.y);
    a0.x += w0 * x0.x; a0.y += w0 * x0.y; a0.z += w0 * x0.z; a0.w += w0 * x0.w;
    a1.x += w1 * x1.x; a1.y += w1 * x1.y; a1.z += w1 * x1.z; a1.w += w1 * x1.w;
    a2.x += w2 * x2.x; a2.y += w2 * x2.y; a2.z += w2 * x2.z; a2.w += w2 * x2.w;
    a3.x += w3 * x3.x; a3.y += w3 * x3.y; a3.z += w3 * x3.z; a3.w += w3 * x3.w;
  }
  for (; i < end; i += 8) {
    int2 en = csc[i];
    float w = __int_as_float(en.y);
    float4 x = *((const float4*)(Esc + (size_t)en.x * DIM) + l);
    a0.x += w * x.x; a0.y += w * x.y; a0.z += w * x.z; a0.w += w * x.w;
  }
  a0.x += a1.x + a2.x + a3.x;
  a0.y += a1.y + a2.y + a3.y;
  a0.z += a1.z + a2.z + a3.z;
  a0.w += a1.w + a2.w + a3.w;
  red[g][l] = a0;
  __syncthreads();
  if (g == 0) {
    float4 o = red[0][l];
#pragma unroll
    for (int gg = 1; gg < 8; ++gg) {
      float4 t = red[gg][l];
      o.x += t.x; o.y += t.y; o.z += t.z; o.w += t.w;
    }
    float inv = de_inv[e];
    o.x *= inv; o.y *= inv; o.z *= inv; o.w *= inv;
    *((float4*)(HXde + (size_t)e * DIM) + l) = o;
  }
}

// pass C fused with gene_ids gather; 4 groups, 2-deep unroll (proven form)
__global__ void k_gene(const int* __restrict__ gene_ids, const int* __restrict__ row_start,
                       const int* __restrict__ row_cnt, const int2* __restrict__ csr,
                       const float* __restrict__ HXde, const float* __restrict__ dv_inv,
                       float* __restrict__ Xg) {
  __shared__ float4 red[4][32];
  int bm = blockIdx.x;
  int gene = gene_ids[bm];
  int s = row_start[gene], n = row_cnt[gene];
  int end = s + n;
  int g = threadIdx.x >> 5, l = threadIdx.x & 31;
  float4 a0 = make_float4(0.f, 0.f, 0.f, 0.f);
  float4 a1 = make_float4(0.f, 0.f, 0.f, 0.f);
  int i = s + g;
  for (; i + 4 < end; i += 8) {
    int2 e0 = csr[i];
    int2 e1 = csr[i + 4];
    float4 x0 = *((const float4*)(HXde + (size_t)e0.x * DIM) + l);
    float4 x1 = *((const float4*)(HXde + (size_t)e1.x * DIM) + l);
    float v0 = __int_as_float(e0.y), v1 = __int_as_float(e1.y);
    a0.x += v0 * x0.x; a0.y += v0 * x0.y; a0.z += v0 * x0.z; a0.w += v0 * x0.w;
    a1.x += v1 * x1.x; a1.y += v1 * x1.y; a1.z += v1 * x1.z; a1.w += v1 * x1.w;
  }
  for (; i < end; i += 4) {
    int2 en = csr[i];
    float v = __int_as_float(en.y);
    float4 x = *((const float4*)(HXde + (size_t)en.x * DIM) + l);
    a0.x += v * x.x; a0.y += v * x.y; a0.z += v * x.z; a0.w += v * x.w;
  }
  a0.x += a1.x; a0.y += a1.y; a0.z += a1.z; a0.w += a1.w;
  red[g][l] = a0;
  __syncthreads();
  if (g == 0) {
    float4 a = red[0][l], b = red[1][l], c = red[2][l], d = red[3][l];
    float dvg = dv_inv[gene];
    float4 o;
    o.x = (a.x + b.x + c.x + d.x) * dvg;
    o.y = (a.y + b.y + c.y + d.y) * dvg;
    o.z = (a.z + b.z + c.z + d.z) * dvg;
    o.w = (a.w + b.w + c.w + d.w) * dvg;
    *((float4*)(Xg + (size_t)bm * DIM) + l) = o;
  }
}

// rep[b,p,d] = (sum_m Xg[b,m,d]*mask[m,p]) / max(cnt[p],1)
#define PT 20
__global__ void k_pathway(const int* __restrict__ gene_ids,
                          const float* __restrict__ gene_pathway,
                          const float* __restrict__ Xg, float* __restrict__ rep) {
  int b = blockIdx.y;
  int p0 = blockIdx.x * PT;
  int d = threadIdx.x;
  float acc[PT], cnt[PT];
#pragma unroll
  for (int pp = 0; pp < PT; ++pp) { acc[pp] = 0.f; cnt[pp] = 0.f; }
  for (int m = 0; m < MM; ++m) {
    int g = gene_ids[b * MM + m];
    float x = Xg[(size_t)(b * MM + m) * DIM + d];
    const float* mrow = gene_pathway + (size_t)g * NPATH + p0;
#pragma unroll
    for (int pp = 0; pp < PT; ++pp) {
      float mv = mrow[pp];
      acc[pp] += mv * x;
      cnt[pp] += mv;
    }
  }
#pragma unroll
  for (int pp = 0; pp < PT; ++pp) {
    rep[((size_t)b * NPATH + p0 + pp) * DIM + d] = acc[pp] / fmaxf(cnt[pp], 1.f);
  }
}

// ctxW[b,j] = sum_k ctx[b,k] * W1[D+k, j]
__global__ void k_ctxw(const int* __restrict__ context_ids,
                       const float* __restrict__ treatment_embed,
                       const float* __restrict__ W1, float* __restrict__ ctxW) {
  __shared__ float ctx_s[DIM];
  int b = blockIdx.x, j = threadIdx.x;
  ctx_s[j] = treatment_embed[context_ids[b] * DIM + j];
  __syncthreads();
  float acc = 0.f;
  for (int k = 0; k < DIM; ++k) acc += ctx_s[k] * W1[(DIM + k) * DIM + j];
  ctxW[b * DIM + j] = acc;
}

// scores[b,p] = tanh(rep@W1_top + ctxW + b1) @ W2 + b2
#define PT2 10
__global__ void k_attn(const float* __restrict__ rep, const float* __restrict__ ctxW,
                       const float* __restrict__ W1, const float* __restrict__ b1,
                       const float* __restrict__ W2, const float* __restrict__ b2,
                       float* __restrict__ scores) {
  __shared__ float in_s[PT2][DIM];
  __shared__ float part[PT2][2];
  int b = blockIdx.y;
  int p0 = blockIdx.x * PT2;
  int j = threadIdx.x;
  int lane = j & 63, wid = j >> 6;
#pragma unroll
  for (int pp = 0; pp < PT2; ++pp)
    in_s[pp][j] = rep[((size_t)b * NPATH + p0 + pp) * DIM + j];
  __syncthreads();
  float base = b1[j] + ctxW[b * DIM + j];
  float acc[PT2];
#pragma unroll
  for (int pp = 0; pp < PT2; ++pp) acc[pp] = base;
  for (int k = 0; k < DIM; ++k) {
    float w1 = W1[k * DIM + j];
#pragma unroll
    for (int pp = 0; pp < PT2; ++pp) acc[pp] += in_s[pp][k] * w1;
  }
  float w2 = W2[j];
#pragma unroll
  for (int pp = 0; pp < PT2; ++pp) {
    float t = tanhf(acc[pp]) * w2;
    t = wred_sum(t);
    if (lane == 0) part[pp][wid] = t;
  }
  __syncthreads();
  if (j < PT2) scores[b * NPATH + p0 + j] = part[j][0] + part[j][1] + b2[0];
}

// softmax + z0 + z + risk, one block per b (128 threads)
__global__ void k_final(const float* __restrict__ scores, const float* __restrict__ rep,
                        const float* __restrict__ latent_W, const float* __restrict__ latent_b,
                        const float* __restrict__ risk_W, const float* __restrict__ risk_b,
                        float* __restrict__ out) {
  __shared__ float w_s[NPATH];
  __shared__ float z0_s[DIM];
  __shared__ float red_max[2], red_sum[2], red_risk[2];
  int b = blockIdx.x, t = threadIdx.x;
  int lane = t & 63, wid = t >> 6;
  float lmax = -3.4e38f;
  for (int p = t; p < NPATH; p += 128) {
    float s = scores[b * NPATH + p];
    w_s[p] = s;
    lmax = fmaxf(lmax, s);
  }
  lmax = wred_max(lmax);
  if (lane == 0) red_max[wid] = lmax;
  __syncthreads();
  float bmax = fmaxf(red_max[0], red_max[1]);
  float lsum = 0.f;
  for (int p = t; p < NPATH; p += 128) {
    float e = expf(w_s[p] - bmax);
    w_s[p] = e;
    lsum += e;
  }
  lsum = wred_sum(lsum);
  if (lane == 0) red_sum[wid] = lsum;
  __syncthreads();
  float inv = 1.f / (red_sum[0] + red_sum[1]);
  float z0 = 0.f;
  int d = t;
#pragma unroll 4
  for (int p = 0; p < NPATH; ++p) z0 += w_s[p] * rep[((size_t)b * NPATH + p) * DIM + d];
  z0 *= inv;
  z0_s[d] = z0;
  __syncthreads();
  float z = latent_b[t];
  for (int dd = 0; dd < DIM; ++dd) z += z0_s[dd] * latent_W[dd * DIM + t];
  out[BB + b * DIM + t] = z;
  float r = z * risk_W[t];
  r = wred_sum(r);
  if (lane == 0) red_risk[wid] = r;
  __syncthreads();
  if (t == 0) out[b] = red_risk[0] + red_risk[1] + risk_b[0];
}

extern "C" void kernel_launch(void* const* d_in, const int* in_sizes, int n_in,
                              void* d_out, int out_size, void* d_ws, size_t ws_size,
                              hipStream_t stream) {
  const int* gene_ids = (const int*)d_in[0];
  const int* context_ids = (const int*)d_in[1];
  const int* H_rows = (const int*)d_in[2];
  const int* H_cols = (const int*)d_in[3];
  const float* H_vals = (const float*)d_in[4];
  const float* gene_embed = (const float*)d_in[5];
  const float* treatment_embed = (const float*)d_in[6];
  const float* gene_pathway = (const float*)d_in[7];
  const float* W1 = (const float*)d_in[8];
  const float* b1 = (const float*)d_in[9];
  const float* W2 = (const float*)d_in[10];
  const float* b2 = (const float*)d_in[11];
  const float* latent_W = (const float*)d_in[12];
  const float* latent_b = (const float*)d_in[13];
  const float* risk_W = (const float*)d_in[14];
  const float* risk_b = (const float*)d_in[15];
  float* out = (float*)d_out;

  char* ws = (char*)d_ws;
  // --- meta (live whole pipeline) ---
  float* dv_inv = (float*)(ws + 0);             // 200000 -> 200000
  float* de_inv = (float*)(ws + 200000);        // 20000 -> 220000
  int* row_cnt = (int*)(ws + 220000);           // 200000 -> 420000
  int* row_start = (int*)(ws + 420000);         // 200000 -> 620000
  int* col_cnt = (int*)(ws + 620000);           // 20000 -> 640000
  int* col_start = (int*)(ws + 640000);         // 20000 -> 660000
  int* ccpre = (int*)(ws + 660000);             // 256*5000*4 = 5120000 -> 5780000
  float* scores = (float*)(ws + 5780000);       // 128000 -> 5908000
  float* ctxW = (float*)(ws + 5908000);         // 32768 -> 5940768 (pad 5940800)
  // --- memset zone ---
  int* row_cur = (int*)(ws + 5940800);          // 200000 -> 6140800
  unsigned* bitmap = (unsigned*)(ws + 6140800); // 6272 -> 6147072
  // --- sparse structures (written after reduce) ---
  int2* csc = (int2*)(ws + 6147072);            // 12800000 -> 18947072
  int2* csr = (int2*)(ws + 18959360);           // 3200000 -> 22159360
  float* HXde = (float*)(ws + 22159360);        // 2560000 -> 24719360
  float* Esc = (float*)(ws + 24719360);         // 25600000 -> 50319360
  // --- hist partials: ALIAS csc/csr/HXde/Esc-head (dead after k_reduce) ---
  float* pdv = (float*)(ws + 6147072);          // 32*50048*4 -> 12553216
  int* pcnt = (int*)(ws + 12553216);            // 32*50048*4 -> 18959360
  int* pccnt = (int*)(ws + 18959360);           // 256*5000*4 -> 24079360
  float* pcsum = (float*)(ws + 24079360);       // 256*5000*4 -> 29199360
  // --- Xg/rep ALIAS Esc (dead after k_edge) ---
  float* Xg = (float*)(ws + 24719360);          // 6553600 -> 31272960 (written in k_gene)
  float* rep = (float*)(ws + 31272960);         // 16384000 -> 47656960 (written in k_pathway)

  hipMemsetAsync(ws + 5940800, 0, 206272, stream);  // row_cur + bitmap

  k_mark<<<(BMN + 255) / 256, 256, 0, stream>>>(gene_ids, bitmap);
  k_hist_row<<<dim3(NCH, 8), 1024, 0, stream>>>(H_rows, H_vals, bitmap, pdv, pcnt);
  k_hist_col<<<CCH, 1024, 0, stream>>>(H_cols, H_vals, pccnt, pcsum);
  k_reduce<<<(NGENES + NEDGES + 255) / 256, 256, 0, stream>>>(
      pdv, pcnt, pccnt, pcsum, dv_inv, row_cnt, col_cnt, de_inv, ccpre);
  k_scan2<<<2, 1024, 0, stream>>>(col_cnt, col_start, row_cnt, row_start);
  k_escale<<<6250, 256, 0, stream>>>(gene_embed, dv_inv, Esc);
  k_place<<<CCH, 1024, 0, stream>>>(H_rows, H_cols, H_vals, col_start, ccpre,
                                    row_start, row_cur, bitmap, csc, csr);
  k_edge<<<NEDGES, 256, 0, stream>>>(col_start, csc, Esc, de_inv, HXde);
  k_gene<<<BMN, 128, 0, stream>>>(gene_ids, row_start, row_cnt, csr, HXde, dv_inv, Xg);
  k_pathway<<<dim3(NPATH / PT, BB), DIM, 0, stream>>>(gene_ids, gene_pathway, Xg, rep);
  k_ctxw<<<BB, DIM, 0, stream>>>(context_ids, treatment_embed, W1, ctxW);
  k_attn<<<dim3(NPATH / PT2, BB), DIM, 0, stream>>>(rep, ctxW, W1, b1, W2, b2, scores);
  k_final<<<BB, DIM, 0, stream>>>(scores, rep, latent_W, latent_b, risk_W, risk_b, out);
}